// Round 12
// baseline (464.684 us; speedup 1.0000x reference)
//
#include <hip/hip_runtime.h>
#include <hip/hip_bf16.h>
#include <stdint.h>

// LinearAttentionBlock: B=2,T=4096,D=1024,H=8,DK=DV=128,INTER=4096,CHUNK=128
// Round 12: k_gemm128 -- 128x128 tile, 256 thr (4 waves), 64KB LDS ->
// 2 blocks/CU. Counted vmcnt(8) double-buffer; MFMAs placed after the
// barriers so the co-resident block's MFMA stretch covers stall windows
// (m97/m114 mechanism, unavailable at 1 block/CU). gate/up interleave
// regranularized to 64-col pairs for the 128-wide tile.

typedef __hip_bfloat16 bf16;
typedef __bf16 bf16x8 __attribute__((ext_vector_type(8)));
typedef float f32x4 __attribute__((ext_vector_type(4)));

union Frag {
  uint4 u;
  bf16x8 b;
  unsigned short s[8];
};

__device__ __forceinline__ float bf2f(unsigned short v) {
  union { unsigned int u; float f; } c;
  c.u = (unsigned int)v << 16;
  return c.f;
}
__device__ __forceinline__ unsigned short f2bf(float f) {
  union { float f; unsigned int u; } c;
  c.f = f;
  unsigned int u = c.u;
  u += 0x7fffu + ((u >> 16) & 1u);
  return (unsigned short)(u >> 16);
}

__device__ __forceinline__ void gload16(const unsigned short* g, unsigned short* l) {
  __builtin_amdgcn_global_load_lds(
      (const __attribute__((address_space(1))) unsigned int*)g,
      (__attribute__((address_space(3))) unsigned int*)l, 16, 0, 0);
}

// ---------------- RMSNorm: f32 [rows][1024] -> bf16 ------------------------
__global__ __launch_bounds__(256) void k_rmsnorm(const float* __restrict__ x,
                                                 const float* __restrict__ w,
                                                 bf16* __restrict__ out) {
  const int row = blockIdx.x;
  const int t = threadIdx.x;
  float4 v = reinterpret_cast<const float4*>(x + (size_t)row * 1024)[t];
  float ss = v.x * v.x + v.y * v.y + v.z * v.z + v.w * v.w;
#pragma unroll
  for (int o = 32; o > 0; o >>= 1) ss += __shfl_xor(ss, o, 64);
  __shared__ float red[4];
  if ((t & 63) == 0) red[t >> 6] = ss;
  __syncthreads();
  float tot = red[0] + red[1] + red[2] + red[3];
  float sc = rsqrtf(tot * (1.f / 1024.f) + 1e-5f);
  float4 wv = reinterpret_cast<const float4*>(w)[t];
  ushort4 o4;
  o4.x = f2bf(v.x * sc * wv.x);
  o4.y = f2bf(v.y * sc * wv.y);
  o4.z = f2bf(v.z * sc * wv.z);
  o4.w = f2bf(v.w * sc * wv.w);
  reinterpret_cast<ushort4*>(out + (size_t)row * 1024)[t] = o4;
}

// ---- batched 1024x1024 transpose+convert: z selects (src,dst) pair ---------
struct TP4 {
  const float* s[4];
  bf16* d[4];
};
__global__ __launch_bounds__(256) void k_transpose_w4(TP4 p) {
  __shared__ float tile[32][33];
  const int z = blockIdx.z;
  const float* W = p.s[z];
  unsigned short* WTu = (unsigned short*)p.d[z];
  const int bx = blockIdx.x * 32;
  const int by = blockIdx.y * 32;
  const int tx = threadIdx.x, ty = threadIdx.y;  // (32,8)
#pragma unroll
  for (int i = 0; i < 4; i++)
    tile[ty + i * 8][tx] = W[(size_t)(by + ty + i * 8) * 1024 + bx + tx];
  __syncthreads();
#pragma unroll
  for (int i = 0; i < 4; i++)
    WTu[(size_t)(bx + ty + i * 8) * 1024 + by + tx] = f2bf(tile[tx][ty + i * 8]);
}

// ------------- Wd transpose: f32 [4096][1024] -> bf16 [1024][4096] ----------
__global__ __launch_bounds__(256) void k_transpose_w(const float* __restrict__ W,
                                                     bf16* __restrict__ WT,
                                                     int R, int C) {
  __shared__ float tile[32][33];
  const int bx = blockIdx.x * 32;
  const int by = blockIdx.y * 32;
  const int tx = threadIdx.x, ty = threadIdx.y;
#pragma unroll
  for (int i = 0; i < 4; i++)
    tile[ty + i * 8][tx] = W[(size_t)(by + ty + i * 8) * C + bx + tx];
  __syncthreads();
  unsigned short* WTu = (unsigned short*)WT;
#pragma unroll
  for (int i = 0; i < 4; i++)
    WTu[(size_t)(bx + ty + i * 8) * R + by + tx] = f2bf(tile[tx][ty + i * 8]);
}

// ------ gate/up interleaved transpose (64-col granularity) ------------------
// dst row f(c) = (c>>6)*128 + which*64 + (c&63); ld = 1024.
__global__ __launch_bounds__(256) void k_transpose_wgu(const float* __restrict__ Wg,
                                                       const float* __restrict__ Wu,
                                                       bf16* __restrict__ WT) {
  __shared__ float tile[32][33];
  const int which = blockIdx.z;
  const float* W = which ? Wu : Wg;
  const int bx = blockIdx.x * 32;
  const int by = blockIdx.y * 32;
  const int tx = threadIdx.x, ty = threadIdx.y;
#pragma unroll
  for (int i = 0; i < 4; i++)
    tile[ty + i * 8][tx] = W[(size_t)(by + ty + i * 8) * 4096 + bx + tx];
  __syncthreads();
  unsigned short* WTu = (unsigned short*)WT;
#pragma unroll
  for (int i = 0; i < 4; i++) {
    const int c = bx + ty + i * 8;
    const int fr = ((c >> 6) << 7) + which * 64 + (c & 63);
    WTu[(size_t)fr * 1024 + by + tx] = f2bf(tile[tx][ty + i * 8]);
  }
}

// ============ 128x128 GEMM, 2 blocks/CU: C[M,N] = A[M,K] x BT[N,K] ==========
// 256 thr = 4 waves (2 wr x 2 wc), per-wave 64x64 out. BK=64, 2-slot dbuf
// (64KB LDS). Per K-tile: 16 ds_read -> lgkm(0) -> bar -> stage t+2 (8
// gload16) -> vmcnt(8) -> bar -> 32 MFMA (after barriers: co-block overlap).
// EPI: 0 = bf16 store; 1 = f32 + residual; 3 = silu(gate)*up (64-col pairs).
template <int EPI>
__global__ __launch_bounds__(256, 2) void k_gemm128(const bf16* __restrict__ A, int lda,
                                                    const bf16* __restrict__ BT,
                                                    const float* __restrict__ res,
                                                    void* __restrict__ Cout,
                                                    int N, int K) {
  constexpr int SLOTSZ = 16384;  // shorts: A 8192 + B 8192
  __shared__ __align__(16) unsigned short lds[2 * SLOTSZ];  // 64 KB

  const int gx = gridDim.x;
  const int nwg = gx * gridDim.y;
  const int lin = blockIdx.y * gx + blockIdx.x;
  const int swz = (lin & 7) * (nwg >> 3) + (lin >> 3);
  const int bm = (swz / gx) * 128, bn = (swz % gx) * 128;

  const int t = threadIdx.x;
  const int wid = t >> 6, lane = t & 63;
  const int wr = wid >> 1, wc = wid & 1;
  const int lm = lane & 15, kg = lane >> 4;
  const int x0 = ((kg ^ (lm & 7)) << 3);
  const int x1 = (((4 + kg) ^ (lm & 7)) << 3);
  const int srow = t >> 3;                        // row within 32-row group
  const int scolS = (((t & 7) ^ (srow & 7)) << 3);  // pre-swizzled src col

  const unsigned short* Ab = (const unsigned short*)A;
  const unsigned short* Bb = (const unsigned short*)BT;

  // stage K-tile tt into slot s: 4 A-gloads + 4 B-gloads (8 total, FIFO)
  auto stage = [&](int s, int tt) {
#pragma unroll
    for (int g = 0; g < 4; g++)
      gload16(Ab + (size_t)(bm + g * 32 + srow) * lda + (size_t)tt * 64 + scolS,
              &lds[s * SLOTSZ + g * 2048 + wid * 512]);
#pragma unroll
    for (int g = 0; g < 4; g++)
      gload16(Bb + (size_t)(bn + g * 32 + srow) * K + (size_t)tt * 64 + scolS,
              &lds[s * SLOTSZ + 8192 + g * 2048 + wid * 512]);
  };

  f32x4 acc[4][4] = {};
  Frag af[4][2], bf[4][2];

  const int NT = K / 64;
  stage(0, 0);
  stage(1, 1);
  asm volatile("s_waitcnt vmcnt(8)" ::: "memory");  // slot0 complete
  __builtin_amdgcn_s_barrier();

  for (int i = 0; i < NT; i++) {
    const int s = i & 1;
    const int ab = s * SLOTSZ;
    // frag loads (tile i, guaranteed resident)
#pragma unroll
    for (int m = 0; m < 4; m++) {
      const int r = (wr * 64 + m * 16 + lm) * 64;
      af[m][0].u = *(const uint4*)&lds[ab + r + x0];
      af[m][1].u = *(const uint4*)&lds[ab + r + x1];
    }
#pragma unroll
    for (int n = 0; n < 4; n++) {
      const int r = 8192 + (wc * 64 + n * 16 + lm) * 64;
      bf[n][0].u = *(const uint4*)&lds[ab + r + x0];
      bf[n][1].u = *(const uint4*)&lds[ab + r + x1];
    }
    asm volatile("s_waitcnt lgkmcnt(0)" ::: "memory");  // reads retired
    __builtin_amdgcn_s_barrier();                       // all waves done reading slot s
    if (i + 2 < NT) {
      stage(s, i + 2);                                  // overwrite slot s
      asm volatile("s_waitcnt vmcnt(8)" ::: "memory");  // tile i+1 complete
    } else {
      asm volatile("s_waitcnt vmcnt(0)" ::: "memory");
    }
    __builtin_amdgcn_s_barrier();                       // slot s^1 readable next iter
    __builtin_amdgcn_s_setprio(1);
#pragma unroll
    for (int m = 0; m < 4; m++)
#pragma unroll
      for (int n = 0; n < 4; n++) {
        acc[m][n] = __builtin_amdgcn_mfma_f32_16x16x32_bf16(af[m][0].b, bf[n][0].b,
                                                            acc[m][n], 0, 0, 0);
        acc[m][n] = __builtin_amdgcn_mfma_f32_16x16x32_bf16(af[m][1].b, bf[n][1].b,
                                                            acc[m][n], 0, 0, 0);
      }
    __builtin_amdgcn_s_setprio(0);
  }

  // ---- epilogue (LDS-routed, coalesced) ----
  if constexpr (EPI == 1) {
    float* fl = (float*)lds;  // [64][128] f32 = 32KB
    float* Co = (float*)Cout;
#pragma unroll
    for (int p = 0; p < 2; p++) {
      __syncthreads();
      if (wr == p) {
#pragma unroll
        for (int m = 0; m < 4; m++)
#pragma unroll
          for (int n = 0; n < 4; n++)
#pragma unroll
            for (int r = 0; r < 4; r++)
              fl[(m * 16 + kg * 4 + r) * 128 + wc * 64 + n * 16 + lm] = acc[m][n][r];
      }
      __syncthreads();
#pragma unroll
      for (int j = 0; j < 8; j++) {
        const int idx = t + j * 256;
        const int row = idx >> 5, c4 = (idx & 31) << 2;
        const size_t o = (size_t)(bm + p * 64 + row) * N + bn + c4;
        float4 v = *(const float4*)&fl[row * 128 + c4];
        float4 rv = *(const float4*)&res[o];
        v.x += rv.x; v.y += rv.y; v.z += rv.z; v.w += rv.w;
        *(float4*)&Co[o] = v;
      }
    }
  } else {
    // acc -> [128][128] bf16 tile in LDS (32KB)
    __syncthreads();
#pragma unroll
    for (int m = 0; m < 4; m++)
#pragma unroll
      for (int n = 0; n < 4; n++)
#pragma unroll
        for (int r = 0; r < 4; r++)
          lds[(wr * 64 + m * 16 + kg * 4 + r) * 128 + wc * 64 + n * 16 + lm] =
              f2bf(acc[m][n][r]);
    __syncthreads();
    unsigned short* Cu = (unsigned short*)Cout;
    if constexpr (EPI == 0) {
#pragma unroll
      for (int j = 0; j < 8; j++) {
        const int idx = t + j * 256;
        const int row = idx >> 4, seg = idx & 15;
        *(uint4*)(Cu + (size_t)(bm + row) * N + bn + seg * 8) =
            *(const uint4*)&lds[row * 128 + seg * 8];
      }
    } else {  // EPI == 3: act[.][N/2] cols bn/2..+63 = silu(lds[.][0:64])*lds[.][64:128]
      const int No = N >> 1;
#pragma unroll
      for (int j = 0; j < 4; j++) {
        const int idx = t + j * 256;
        const int row = idx >> 3, s8 = (idx & 7) << 3;
        Frag gf, uf, rr;
        gf.u = *(const uint4*)&lds[row * 128 + s8];
        uf.u = *(const uint4*)&lds[row * 128 + 64 + s8];
#pragma unroll
        for (int a = 0; a < 8; a++) {
          float g = bf2f(gf.s[a]);
          float uu = bf2f(uf.s[a]);
          rr.s[a] = f2bf(g / (1.f + __expf(-g)) * uu);
        }
        *(uint4*)(Cu + (size_t)(bm + row) * No + (bn >> 1) + s8) = rr.u;
      }
    }
  }
}

// -------- K_A: per-(b,h,chunk) GT = v^T k AND VT write. grid=512, 256 thr ---
__global__ __launch_bounds__(256) void k_chunk_kv(const bf16* __restrict__ qkv,
                                                  float* __restrict__ G,
                                                  bf16* __restrict__ VT) {
  __shared__ __align__(16) unsigned short ks[128][128];
  __shared__ __align__(16) unsigned short vs[128][136];
  const int idx = blockIdx.x;
  const int cc = idx & 31, bh = idx >> 5, bb = bh >> 3, hh = bh & 7;
  const unsigned short* qkvu = (const unsigned short*)qkv;
  const unsigned short* kp = qkvu + (size_t)(bb * 4096 + cc * 128) * 3072 + 1024 + hh * 128;
  const unsigned short* vp = kp + 1024;
  const int t = threadIdx.x;
#pragma unroll
  for (int i = 0; i < 8; i++) {
    int ch = t + i * 256;
    int r = ch >> 4, c8 = (ch & 15) << 3;
    *(uint4*)&ks[r][c8] = *(const uint4*)(kp + (size_t)r * 3072 + c8);
    *(uint4*)&vs[r][c8] = *(const uint4*)(vp + (size_t)r * 3072 + c8);
  }
  __syncthreads();
  const int dv0 = (t >> 4) * 8, dk0 = (t & 15) * 8;
  float acc[8][8] = {};
  for (int j = 0; j < 128; j++) {
    Frag kf, vf;
    vf.u = *(const uint4*)&vs[j][dv0];
    kf.u = *(const uint4*)&ks[j][dk0];
    float kx[8], vx[8];
#pragma unroll
    for (int a = 0; a < 8; a++) { kx[a] = bf2f(kf.s[a]); vx[a] = bf2f(vf.s[a]); }
#pragma unroll
    for (int a = 0; a < 8; a++)
#pragma unroll
      for (int b2 = 0; b2 < 8; b2++) acc[a][b2] += vx[a] * kx[b2];
  }
  float* Gp = G + (size_t)idx * 16384;
#pragma unroll
  for (int a = 0; a < 8; a++)
#pragma unroll
    for (int b2 = 0; b2 < 8; b2 += 4) {
      float4 w4 = make_float4(acc[a][b2], acc[a][b2 + 1], acc[a][b2 + 2], acc[a][b2 + 3]);
      *(float4*)(Gp + (size_t)(dv0 + a) * 128 + dk0 + b2) = w4;
    }
  unsigned short* vo = (unsigned short*)VT + (size_t)bh * 524288 + cc * 128;
#pragma unroll
  for (int i = 0; i < 8; i++) {
    const int dv = (t >> 4) + i * 16;
    const int r0 = (t & 15) * 8;
    Frag f;
#pragma unroll
    for (int j = 0; j < 8; j++) f.s[j] = vs[r0 + j][dv];
    *(uint4*)(vo + (size_t)dv * 4096 + r0) = f.u;
  }
}

// -------- K_B: exclusive prefix over chunks -> ST bf16. grid=1024 -----------
__global__ __launch_bounds__(256) void k_prefix(const float* __restrict__ G,
                                                bf16* __restrict__ S) {
  const size_t gid = (size_t)blockIdx.x * 256 + threadIdx.x;
  const size_t bh = gid >> 14, e = gid & 16383;
  const float* gp = G + (bh << 5) * 16384 + e;
  unsigned short* sp = (unsigned short*)S + (bh << 5) * 16384 + e;
  float run = 0.f;
  for (int c2 = 0; c2 < 32; c2++) {
    sp[(size_t)c2 << 14] = f2bf(run);
    run += gp[(size_t)c2 << 14];
  }
}

// -------- K_C: MFMA fused chunk attention + per-head RMSNorm ----------------
__global__ __launch_bounds__(256) void k_attn2(const bf16* __restrict__ qkv,
                                               const bf16* __restrict__ VT,
                                               const bf16* __restrict__ ST,
                                               const float* __restrict__ nw,
                                               bf16* __restrict__ A2) {
  __shared__ __align__(16) unsigned short Qs[128][136];
  __shared__ __align__(16) unsigned short Ks[128][136];
  __shared__ __align__(16) unsigned short Bs[128][136];
  __shared__ float red[128][2];

  const int idx = blockIdx.x;
  const int cc = idx & 31, bh = idx >> 5, bb = bh >> 3, hh = bh & 7;
  const size_t rowbase = (size_t)(bb * 4096 + cc * 128);
  const unsigned short* qp = (const unsigned short*)qkv + rowbase * 3072 + hh * 128;
  const unsigned short* kp = qp + 1024;
  const unsigned short* vtp = (const unsigned short*)VT + (size_t)bh * 524288 + cc * 128;
  const unsigned short* stp = (const unsigned short*)ST + ((size_t)idx << 14);

  const int t = threadIdx.x;
  const int wid = t >> 6, lane = t & 63;
  const int wm = (wid >> 1) * 64, wn = (wid & 1) * 64;
  const int lm = lane & 15, kg = lane >> 4;
  const int sr = t >> 4;
  const int sc = (t & 15) << 3;

#pragma unroll
  for (int i = 0; i < 8; i++) {
    int r = sr + i * 16;
    *(uint4*)&Qs[r][sc] = *(const uint4*)(qp + (size_t)r * 3072 + sc);
    *(uint4*)&Ks[r][sc] = *(const uint4*)(kp + (size_t)r * 3072 + sc);
    *(uint4*)&Bs[r][sc] = *(const uint4*)(vtp + (size_t)r * 4096 + sc);
  }
  __syncthreads();

  f32x4 acc[4][4] = {};
#pragma unroll
  for (int kk = 0; kk < 4; kk++) {
    Frag af[4], bfr[4];
#pragma unroll
    for (int i = 0; i < 4; i++) {
      af[i].u = *(const uint4*)&Qs[wm + i * 16 + lm][kk * 32 + kg * 8];
      bfr[i].u = *(const uint4*)&Ks[wn + i * 16 + lm][kk * 32 + kg * 8];
    }
#pragma unroll
    for (int mi = 0; mi < 4; mi++)
#pragma unroll
      for (int ni = 0; ni < 4; ni++)
        acc[mi][ni] = __builtin_amdgcn_mfma_f32_16x16x32_bf16(af[mi].b, bfr[ni].b,
                                                              acc[mi][ni], 0, 0, 0);
  }
  __syncthreads();

#pragma unroll
  for (int mi = 0; mi < 4; mi++)
#pragma unroll
    for (int r = 0; r < 4; r++) {
      const int gi = wm + mi * 16 + kg * 4 + r;
#pragma unroll
      for (int ni = 0; ni < 4; ni++) {
        const int gj = wn + ni * 16 + lm;
        Ks[gi][gj] = f2bf(gj <= gi ? acc[mi][ni][r] : 0.f);
      }
    }
  __syncthreads();

  f32x4 oa[4][4] = {};
#pragma unroll
  for (int kk = 0; kk < 4; kk++) {
    Frag af[4], bfr[4];
#pragma unroll
    for (int i = 0; i < 4; i++) {
      af[i].u = *(const uint4*)&Ks[wm + i * 16 + lm][kk * 32 + kg * 8];
      bfr[i].u = *(const uint4*)&Bs[wn + i * 16 + lm][kk * 32 + kg * 8];
    }
#pragma unroll
    for (int mi = 0; mi < 4; mi++)
#pragma unroll
      for (int ni = 0; ni < 4; ni++)
        oa[mi][ni] = __builtin_amdgcn_mfma_f32_16x16x32_bf16(af[mi].b, bfr[ni].b,
                                                             oa[mi][ni], 0, 0, 0);
  }
  __syncthreads();

#pragma unroll
  for (int i = 0; i < 8; i++) {
    int r = sr + i * 16;
    *(uint4*)&Bs[r][sc] = *(const uint4*)(stp + (size_t)r * 128 + sc);
  }
  __syncthreads();

#pragma unroll
  for (int kk = 0; kk < 4; kk++) {
    Frag af[4], bfr[4];
#pragma unroll
    for (int i = 0; i < 4; i++) {
      af[i].u = *(const uint4*)&Qs[wm + i * 16 + lm][kk * 32 + kg * 8];
      bfr[i].u = *(const uint4*)&Bs[wn + i * 16 + lm][kk * 32 + kg * 8];
    }
#pragma unroll
    for (int mi = 0; mi < 4; mi++)
#pragma unroll
      for (int ni = 0; ni < 4; ni++)
        oa[mi][ni] = __builtin_amdgcn_mfma_f32_16x16x32_bf16(af[mi].b, bfr[ni].b,
                                                             oa[mi][ni], 0, 0, 0);
  }

#pragma unroll
  for (int mi = 0; mi < 4; mi++)
#pragma unroll
    for (int r = 0; r < 4; r++) {
      float ss = 0.f;
#pragma unroll
      for (int ni = 0; ni < 4; ni++) ss += oa[mi][ni][r] * oa[mi][ni][r];
      ss += __shfl_xor(ss, 1, 64);
      ss += __shfl_xor(ss, 2, 64);
      ss += __shfl_xor(ss, 4, 64);
      ss += __shfl_xor(ss, 8, 64);
      if (lm == 0) red[wm + mi * 16 + kg * 4 + r][wid & 1] = ss;
    }
  __syncthreads();

#pragma unroll
  for (int mi = 0; mi < 4; mi++)
#pragma unroll
    for (int r = 0; r < 4; r++) {
      const int gi = wm + mi * 16 + kg * 4 + r;
      const float tot = red[gi][0] + red[gi][1];
      const float scl = rsqrtf(tot * (1.f / 128.f) + 1e-5f);
#pragma unroll
      for (int ni = 0; ni < 4; ni++) {
        const int gj = wn + ni * 16 + lm;
        Ks[gi][gj] = f2bf(oa[mi][ni][r] * scl * nw[gj]);
      }
    }
  __syncthreads();

  unsigned short* A2u = (unsigned short*)A2;
#pragma unroll
  for (int i = 0; i < 8; i++) {
    int r = sr + i * 16;
    *(uint4*)(A2u + (rowbase + r) * 1024 + hh * 128 + sc) = *(const uint4*)&Ks[r][sc];
  }
}

// ---------------------------------------------------------------------------
extern "C" void kernel_launch(void* const* d_in, const int* in_sizes, int n_in,
                              void* d_out, int out_size, void* d_ws, size_t ws_size,
                              hipStream_t stream) {
  const float* x = (const float*)d_in[0];
  const float* anw = (const float*)d_in[1];
  const float* Wq = (const float*)d_in[2];
  const float* Wk = (const float*)d_in[3];
  const float* Wv = (const float*)d_in[4];
  const float* Wo = (const float*)d_in[5];
  const float* onw = (const float*)d_in[6];
  const float* mnw = (const float*)d_in[7];
  const float* Wg = (const float*)d_in[8];
  const float* Wu = (const float*)d_in[9];
  const float* Wd = (const float*)d_in[10];
  float* out = (float*)d_out;

  char* base = (char*)d_ws;
  size_t off = 0;
  auto alloc = [&](size_t bytes) -> char* {
    char* q = base + off;
    off += (bytes + 255) & ~(size_t)255;
    return q;
  };
  bf16* WqkvT = (bf16*)alloc(3072ll * 1024 * 2);
  bf16* WoT   = (bf16*)alloc(1024ll * 1024 * 2);
  bf16* WguT  = (bf16*)alloc(8192ll * 1024 * 2);   // interleaved gate|up (64-col)
  bf16* WdT   = (bf16*)alloc(1024ll * 4096 * 2);
  bf16* h     = (bf16*)alloc(8192ll * 1024 * 2);
  float* x1   = (float*)alloc(8192ll * 1024 * 4);
  char* pool  = alloc(8192ll * 3072 * 2 + 16ll * 32 * 16384 * 4 +
                      16ll * 32 * 16384 * 2 + 16ll * 128 * 4096 * 2);
  bf16* qkv = (bf16*)pool;
  float* G  = (float*)(pool + 8192ll * 3072 * 2);
  bf16* S   = (bf16*)(pool + 8192ll * 3072 * 2 + 16ll * 32 * 16384 * 4);
  bf16* VT  = (bf16*)(pool + 8192ll * 3072 * 2 + 16ll * 32 * 16384 * 4 +
                      16ll * 32 * 16384 * 2);
  bf16* act = (bf16*)pool;  // MLP phase reuse

  const dim3 tb32(32, 8);
  TP4 tp;
  tp.s[0] = Wq; tp.d[0] = WqkvT;
  tp.s[1] = Wk; tp.d[1] = WqkvT + 1024ll * 1024;
  tp.s[2] = Wv; tp.d[2] = WqkvT + 2048ll * 1024;
  tp.s[3] = Wo; tp.d[3] = WoT;
  k_transpose_w4<<<dim3(32, 32, 4), tb32, 0, stream>>>(tp);
  k_transpose_wgu<<<dim3(128, 32, 2), tb32, 0, stream>>>(Wg, Wu, WguT);
  k_transpose_w<<<dim3(32, 128), tb32, 0, stream>>>(Wd, WdT, 4096, 1024);

  // attn sub-block
  k_rmsnorm<<<8192, 256, 0, stream>>>(x, anw, h);
  k_gemm128<0><<<dim3(24, 64), 256, 0, stream>>>(h, 1024, WqkvT, nullptr, qkv, 3072, 1024);
  k_chunk_kv<<<512, 256, 0, stream>>>(qkv, G, VT);
  k_prefix<<<1024, 256, 0, stream>>>(G, S);
  k_attn2<<<512, 256, 0, stream>>>(qkv, VT, S, onw, h);
  k_gemm128<1><<<dim3(8, 64), 256, 0, stream>>>(h, 1024, WoT, x, x1, 1024, 1024);

  // mlp sub-block
  k_rmsnorm<<<8192, 256, 0, stream>>>(x1, mnw, h);
  k_gemm128<3><<<dim3(64, 64), 256, 0, stream>>>(h, 1024, WguT, nullptr, act, 8192, 1024);
  k_gemm128<1><<<dim3(8, 64), 256, 0, stream>>>(act, 4096, WdT, x1, out, 1024, 4096);
}

// Round 13
// 437.501 us; speedup vs baseline: 1.0621x; 1.0621x over previous
//
#include <hip/hip_runtime.h>
#include <hip/hip_bf16.h>
#include <stdint.h>

// LinearAttentionBlock: B=2,T=4096,D=1024,H=8,DK=DV=128,INTER=4096,CHUNK=128
// Round 13: hybrid GEMM dispatch. Measured: 256^2 tile wins gate/up (B-reuse,
// FETCH 270 vs 532 MB); 128^2 2-blocks/CU wins QKV/Wo/down (occupancy overlap,
// K-deep). Both kernels byte-identical to their best-measured versions.

typedef __hip_bfloat16 bf16;
typedef __bf16 bf16x8 __attribute__((ext_vector_type(8)));
typedef float f32x4 __attribute__((ext_vector_type(4)));

union Frag {
  uint4 u;
  bf16x8 b;
  unsigned short s[8];
};

__device__ __forceinline__ float bf2f(unsigned short v) {
  union { unsigned int u; float f; } c;
  c.u = (unsigned int)v << 16;
  return c.f;
}
__device__ __forceinline__ unsigned short f2bf(float f) {
  union { float f; unsigned int u; } c;
  c.f = f;
  unsigned int u = c.u;
  u += 0x7fffu + ((u >> 16) & 1u);
  return (unsigned short)(u >> 16);
}

__device__ __forceinline__ void gload16(const unsigned short* g, unsigned short* l) {
  __builtin_amdgcn_global_load_lds(
      (const __attribute__((address_space(1))) unsigned int*)g,
      (__attribute__((address_space(3))) unsigned int*)l, 16, 0, 0);
}

// ---------------- RMSNorm: f32 [rows][1024] -> bf16 ------------------------
__global__ __launch_bounds__(256) void k_rmsnorm(const float* __restrict__ x,
                                                 const float* __restrict__ w,
                                                 bf16* __restrict__ out) {
  const int row = blockIdx.x;
  const int t = threadIdx.x;
  float4 v = reinterpret_cast<const float4*>(x + (size_t)row * 1024)[t];
  float ss = v.x * v.x + v.y * v.y + v.z * v.z + v.w * v.w;
#pragma unroll
  for (int o = 32; o > 0; o >>= 1) ss += __shfl_xor(ss, o, 64);
  __shared__ float red[4];
  if ((t & 63) == 0) red[t >> 6] = ss;
  __syncthreads();
  float tot = red[0] + red[1] + red[2] + red[3];
  float sc = rsqrtf(tot * (1.f / 1024.f) + 1e-5f);
  float4 wv = reinterpret_cast<const float4*>(w)[t];
  ushort4 o4;
  o4.x = f2bf(v.x * sc * wv.x);
  o4.y = f2bf(v.y * sc * wv.y);
  o4.z = f2bf(v.z * sc * wv.z);
  o4.w = f2bf(v.w * sc * wv.w);
  reinterpret_cast<ushort4*>(out + (size_t)row * 1024)[t] = o4;
}

// ---- batched 1024x1024 transpose+convert: z selects (src,dst) pair ---------
struct TP4 {
  const float* s[4];
  bf16* d[4];
};
__global__ __launch_bounds__(256) void k_transpose_w4(TP4 p) {
  __shared__ float tile[32][33];
  const int z = blockIdx.z;
  const float* W = p.s[z];
  unsigned short* WTu = (unsigned short*)p.d[z];
  const int bx = blockIdx.x * 32;
  const int by = blockIdx.y * 32;
  const int tx = threadIdx.x, ty = threadIdx.y;  // (32,8)
#pragma unroll
  for (int i = 0; i < 4; i++)
    tile[ty + i * 8][tx] = W[(size_t)(by + ty + i * 8) * 1024 + bx + tx];
  __syncthreads();
#pragma unroll
  for (int i = 0; i < 4; i++)
    WTu[(size_t)(bx + ty + i * 8) * 1024 + by + tx] = f2bf(tile[tx][ty + i * 8]);
}

// ------------- Wd transpose: f32 [4096][1024] -> bf16 [1024][4096] ----------
__global__ __launch_bounds__(256) void k_transpose_w(const float* __restrict__ W,
                                                     bf16* __restrict__ WT,
                                                     int R, int C) {
  __shared__ float tile[32][33];
  const int bx = blockIdx.x * 32;
  const int by = blockIdx.y * 32;
  const int tx = threadIdx.x, ty = threadIdx.y;
#pragma unroll
  for (int i = 0; i < 4; i++)
    tile[ty + i * 8][tx] = W[(size_t)(by + ty + i * 8) * C + bx + tx];
  __syncthreads();
  unsigned short* WTu = (unsigned short*)WT;
#pragma unroll
  for (int i = 0; i < 4; i++)
    WTu[(size_t)(bx + ty + i * 8) * R + by + tx] = f2bf(tile[tx][ty + i * 8]);
}

// ------ gate/up interleaved transpose (128-col granularity, for 256^2) ------
// dst row f(c) = (c>>7)*256 + which*128 + (c&127); ld = 1024.
__global__ __launch_bounds__(256) void k_transpose_wgu(const float* __restrict__ Wg,
                                                       const float* __restrict__ Wu,
                                                       bf16* __restrict__ WT) {
  __shared__ float tile[32][33];
  const int which = blockIdx.z;
  const float* W = which ? Wu : Wg;
  const int bx = blockIdx.x * 32;
  const int by = blockIdx.y * 32;
  const int tx = threadIdx.x, ty = threadIdx.y;
#pragma unroll
  for (int i = 0; i < 4; i++)
    tile[ty + i * 8][tx] = W[(size_t)(by + ty + i * 8) * 4096 + bx + tx];
  __syncthreads();
  unsigned short* WTu = (unsigned short*)WT;
#pragma unroll
  for (int i = 0; i < 4; i++) {
    const int c = bx + ty + i * 8;
    const int fr = ((c >> 7) << 8) + which * 128 + (c & 127);
    WTu[(size_t)fr * 1024 + by + tx] = f2bf(tile[tx][ty + i * 8]);
  }
}

// ============== 256x256 8-phase GEMM (round-8/11 schedule) ==================
// EPI: 0 = bf16 store; 1 = f32 + residual; 3 = silu(gate)*up interleaved.
template <int BM, int EPI>
__global__ __launch_bounds__(512, 2) void k_gemm256(const bf16* __restrict__ A, int lda,
                                                    const bf16* __restrict__ BT,
                                                    const float* __restrict__ res,
                                                    void* __restrict__ Cout,
                                                    int N, int K) {
  constexpr int MR = BM / 64;
  constexpr int ASZ = BM * 64;
  constexpr int AHALF = BM * 32;
  constexpr int SLOTSZ = ASZ + 16384;
  __shared__ __align__(16) unsigned short lds[2 * SLOTSZ];

  const int gx = gridDim.x;
  const int nwg = gx * gridDim.y;
  const int lin = blockIdx.y * gx + blockIdx.x;
  const int swz = (lin & 7) * (nwg >> 3) + (lin >> 3);
  const int bm = (swz / gx) * BM, bn = (swz % gx) * 256;

  const int t = threadIdx.x;
  const int wid = t >> 6, lane = t & 63;
  const int wr = wid >> 2, wc = wid & 3;
  const int lm = lane & 15, kg = lane >> 4;
  const int x0 = ((kg ^ (lm & 7)) << 3);
  const int x1 = (((4 + kg) ^ (lm & 7)) << 3);
  const int scolS = (((lane & 7) ^ ((lane >> 3) & 7)) << 3);

  const unsigned short* Ab = (const unsigned short*)A;
  const unsigned short* Bb = (const unsigned short*)BT;

  auto stA = [&](int slot, int h, int tt) {
    if constexpr (BM == 256) {
      const unsigned short* g = Ab + (size_t)(bm + h * 64 + wid * 8 + (lane >> 3)) * lda +
                                (size_t)tt * 64 + scolS;
      unsigned short* d = &lds[slot * SLOTSZ + h * 8192 + wid * 512];
      gload16(g, d);
      gload16(g + (size_t)128 * lda, d + 4096);
    } else {
      const int i0 = wid * 8 + (lane >> 3);
      const unsigned short* g = Ab +
          (size_t)(bm + ((i0 >> 5) << 6) + h * 32 + (i0 & 31)) * lda +
          (size_t)tt * 64 + scolS;
      gload16(g, &lds[slot * SLOTSZ + h * 4096 + wid * 512]);
    }
  };
  auto stB = [&](int slot, int h, int tt) {
    const int i0 = wid * 8 + (lane >> 3);
    const unsigned short* g = Bb +
        (size_t)(bn + ((i0 >> 5) << 6) + h * 32 + (i0 & 31)) * K +
        (size_t)tt * 64 + scolS;
    unsigned short* d = &lds[slot * SLOTSZ + ASZ + h * 8192 + wid * 512];
    gload16(g, d);
    gload16(g + (size_t)128 * K, d + 4096);
  };
  auto vmn = [&]() {
    if constexpr (BM == 256) asm volatile("s_waitcnt vmcnt(8)" ::: "memory");
    else                     asm volatile("s_waitcnt vmcnt(6)" ::: "memory");
  };
  auto vm0 = [&]() { asm volatile("s_waitcnt vmcnt(0)" ::: "memory"); };

  f32x4 acc[2 * MR][4] = {};
  Frag af[MR][2], bf0[2][2], bf1[2][2];

#define LOADA(SLOT, MH)                                                        \
  {                                                                            \
    const int abase = (SLOT)*SLOTSZ + (MH)*AHALF + wr * (AHALF / 2) + lm * 64; \
    _Pragma("unroll") for (int m = 0; m < MR; m++) {                           \
      af[m][0].u = *(const uint4*)&lds[abase + m * 1024 + x0];                 \
      af[m][1].u = *(const uint4*)&lds[abase + m * 1024 + x1];                 \
    }                                                                          \
  }
#define LOADB(SLOT, NH, BF)                                                    \
  {                                                                            \
    const int bbase = (SLOT)*SLOTSZ + ASZ + (NH)*8192 + wc * 2048 + lm * 64;   \
    _Pragma("unroll") for (int n = 0; n < 2; n++) {                            \
      BF[n][0].u = *(const uint4*)&lds[bbase + n * 1024 + x0];                 \
      BF[n][1].u = *(const uint4*)&lds[bbase + n * 1024 + x1];                 \
    }                                                                          \
  }
#define PH(LOADS, STAGES, VMW, MH, NH, BF)                                     \
  {                                                                            \
    LOADS;                                                                     \
    STAGES;                                                                    \
    VMW;                                                                       \
    __builtin_amdgcn_s_setprio(1);                                             \
    _Pragma("unroll") for (int m = 0; m < MR; m++)                             \
    _Pragma("unroll") for (int n = 0; n < 2; n++) {                            \
      f32x4& ac = acc[(MH)*MR + m][(NH)*2 + n];                                \
      ac = __builtin_amdgcn_mfma_f32_16x16x32_bf16(af[m][0].b, BF[n][0].b, ac, 0, 0, 0); \
      ac = __builtin_amdgcn_mfma_f32_16x16x32_bf16(af[m][1].b, BF[n][1].b, ac, 0, 0, 0); \
    }                                                                          \
    __builtin_amdgcn_s_setprio(0);                                             \
    __builtin_amdgcn_s_barrier();                                              \
  }

  stA(0, 0, 0); stB(0, 0, 0); stB(0, 1, 0); stA(0, 1, 0);
  stA(1, 0, 1); stB(1, 0, 1); stB(1, 1, 1); stA(1, 1, 1);
  vmn();
  __builtin_amdgcn_s_barrier();

  const int NI = K / 128;
  for (int i = 0; i < NI; i++) {
    const int u = 2 * i;
    const bool st = (i + 1 < NI);
    PH(LOADA(0, 0); LOADB(0, 0, bf0), , , 0, 0, bf0)
    PH(LOADB(0, 1, bf1), { if (st) { stA(0, 0, u + 2); stB(0, 0, u + 2); } }, , 0, 1, bf1)
    PH(LOADA(0, 1), { if (st) stB(0, 1, u + 2); }, , 1, 0, bf0)
    PH(, { if (st) stA(0, 1, u + 2); }, if (st) { vmn(); } else { vm0(); }, 1, 1, bf1)
    PH(LOADA(1, 0); LOADB(1, 0, bf0), , , 0, 0, bf0)
    PH(LOADB(1, 1, bf1), { if (st) { stA(1, 0, u + 3); stB(1, 0, u + 3); } }, , 0, 1, bf1)
    PH(LOADA(1, 1), { if (st) stB(1, 1, u + 3); }, , 1, 0, bf0)
    PH(, { if (st) stA(1, 1, u + 3); }, if (st) { vmn(); }, 1, 1, bf1)
  }
#undef PH
#undef LOADA
#undef LOADB

  if constexpr (EPI == 1) {
    constexpr int PR = BM / 2;
    float* fl = (float*)lds;
    float* Co = (float*)Cout;
#pragma unroll
    for (int p = 0; p < 2; p++) {
      if (wr == p) {
#pragma unroll
        for (int m = 0; m < 2 * MR; m++)
#pragma unroll
          for (int n = 0; n < 4; n++)
#pragma unroll
            for (int r = 0; r < 4; r++)
              fl[(m * 16 + kg * 4 + r) * 256 + wc * 64 + n * 16 + lm] = acc[m][n][r];
      }
      __syncthreads();
#pragma unroll
      for (int j = 0; j < PR / 8; j++) {
        const int idx = t + j * 512;
        const int row = idx >> 6, seg = idx & 63;
        const size_t o = (size_t)(bm + p * PR + row) * N + bn + seg * 4;
        float4 v = *(const float4*)&fl[row * 256 + seg * 4];
        float4 rv = *(const float4*)&res[o];
        v.x += rv.x; v.y += rv.y; v.z += rv.z; v.w += rv.w;
        *(float4*)&Co[o] = v;
      }
      __syncthreads();
    }
  } else {
#pragma unroll
    for (int m = 0; m < 2 * MR; m++)
#pragma unroll
      for (int n = 0; n < 4; n++)
#pragma unroll
        for (int r = 0; r < 4; r++)
          lds[(wr * (BM / 2) + m * 16 + kg * 4 + r) * 256 + wc * 64 + n * 16 + lm] =
              f2bf(acc[m][n][r]);
    __syncthreads();
    unsigned short* Cu = (unsigned short*)Cout;
    if constexpr (EPI == 0) {
#pragma unroll
      for (int j = 0; j < BM / 16; j++) {
        const int idx = t + j * 512;
        const int row = idx >> 5, seg = idx & 31;
        *(uint4*)(Cu + (size_t)(bm + row) * N + bn + seg * 8) =
            *(const uint4*)&lds[row * 256 + seg * 8];
      }
    } else {
      const int No = N >> 1;
#pragma unroll
      for (int j = 0; j < BM / 32; j++) {
        const int idx = t + j * 512;
        const int row = idx >> 4, seg = idx & 15;
        Frag gf, uf, rr;
        gf.u = *(const uint4*)&lds[row * 256 + seg * 8];
        uf.u = *(const uint4*)&lds[row * 256 + 128 + seg * 8];
#pragma unroll
        for (int a = 0; a < 8; a++) {
          float g = bf2f(gf.s[a]);
          float uu = bf2f(uf.s[a]);
          rr.s[a] = f2bf(g / (1.f + __expf(-g)) * uu);
        }
        *(uint4*)(Cu + (size_t)(bm + row) * No + (bn >> 1) + seg * 8) = rr.u;
      }
    }
  }
}

// ============ 128x128 GEMM, 2 blocks/CU (round-12) ==========================
// EPI: 0 = bf16 store; 1 = f32 + residual.
template <int EPI>
__global__ __launch_bounds__(256, 2) void k_gemm128(const bf16* __restrict__ A, int lda,
                                                    const bf16* __restrict__ BT,
                                                    const float* __restrict__ res,
                                                    void* __restrict__ Cout,
                                                    int N, int K) {
  constexpr int SLOTSZ = 16384;
  __shared__ __align__(16) unsigned short lds[2 * SLOTSZ];  // 64 KB

  const int gx = gridDim.x;
  const int nwg = gx * gridDim.y;
  const int lin = blockIdx.y * gx + blockIdx.x;
  const int swz = (lin & 7) * (nwg >> 3) + (lin >> 3);
  const int bm = (swz / gx) * 128, bn = (swz % gx) * 128;

  const int t = threadIdx.x;
  const int wid = t >> 6, lane = t & 63;
  const int wr = wid >> 1, wc = wid & 1;
  const int lm = lane & 15, kg = lane >> 4;
  const int x0 = ((kg ^ (lm & 7)) << 3);
  const int x1 = (((4 + kg) ^ (lm & 7)) << 3);
  const int srow = t >> 3;
  const int scolS = (((t & 7) ^ (srow & 7)) << 3);

  const unsigned short* Ab = (const unsigned short*)A;
  const unsigned short* Bb = (const unsigned short*)BT;

  auto stage = [&](int s, int tt) {
#pragma unroll
    for (int g = 0; g < 4; g++)
      gload16(Ab + (size_t)(bm + g * 32 + srow) * lda + (size_t)tt * 64 + scolS,
              &lds[s * SLOTSZ + g * 2048 + wid * 512]);
#pragma unroll
    for (int g = 0; g < 4; g++)
      gload16(Bb + (size_t)(bn + g * 32 + srow) * K + (size_t)tt * 64 + scolS,
              &lds[s * SLOTSZ + 8192 + g * 2048 + wid * 512]);
  };

  f32x4 acc[4][4] = {};
  Frag af[4][2], bf[4][2];

  const int NT = K / 64;
  stage(0, 0);
  stage(1, 1);
  asm volatile("s_waitcnt vmcnt(8)" ::: "memory");
  __builtin_amdgcn_s_barrier();

  for (int i = 0; i < NT; i++) {
    const int s = i & 1;
    const int ab = s * SLOTSZ;
#pragma unroll
    for (int m = 0; m < 4; m++) {
      const int r = (wr * 64 + m * 16 + lm) * 64;
      af[m][0].u = *(const uint4*)&lds[ab + r + x0];
      af[m][1].u = *(const uint4*)&lds[ab + r + x1];
    }
#pragma unroll
    for (int n = 0; n < 4; n++) {
      const int r = 8192 + (wc * 64 + n * 16 + lm) * 64;
      bf[n][0].u = *(const uint4*)&lds[ab + r + x0];
      bf[n][1].u = *(const uint4*)&lds[ab + r + x1];
    }
    asm volatile("s_waitcnt lgkmcnt(0)" ::: "memory");
    __builtin_amdgcn_s_barrier();
    if (i + 2 < NT) {
      stage(s, i + 2);
      asm volatile("s_waitcnt vmcnt(8)" ::: "memory");
    } else {
      asm volatile("s_waitcnt vmcnt(0)" ::: "memory");
    }
    __builtin_amdgcn_s_barrier();
    __builtin_amdgcn_s_setprio(1);
#pragma unroll
    for (int m = 0; m < 4; m++)
#pragma unroll
      for (int n = 0; n < 4; n++) {
        acc[m][n] = __builtin_amdgcn_mfma_f32_16x16x32_bf16(af[m][0].b, bf[n][0].b,
                                                            acc[m][n], 0, 0, 0);
        acc[m][n] = __builtin_amdgcn_mfma_f32_16x16x32_bf16(af[m][1].b, bf[n][1].b,
                                                            acc[m][n], 0, 0, 0);
      }
    __builtin_amdgcn_s_setprio(0);
  }

  if constexpr (EPI == 1) {
    float* fl = (float*)lds;
    float* Co = (float*)Cout;
#pragma unroll
    for (int p = 0; p < 2; p++) {
      __syncthreads();
      if (wr == p) {
#pragma unroll
        for (int m = 0; m < 4; m++)
#pragma unroll
          for (int n = 0; n < 4; n++)
#pragma unroll
            for (int r = 0; r < 4; r++)
              fl[(m * 16 + kg * 4 + r) * 128 + wc * 64 + n * 16 + lm] = acc[m][n][r];
      }
      __syncthreads();
#pragma unroll
      for (int j = 0; j < 8; j++) {
        const int idx = t + j * 256;
        const int row = idx >> 5, c4 = (idx & 31) << 2;
        const size_t o = (size_t)(bm + p * 64 + row) * N + bn + c4;
        float4 v = *(const float4*)&fl[row * 128 + c4];
        float4 rv = *(const float4*)&res[o];
        v.x += rv.x; v.y += rv.y; v.z += rv.z; v.w += rv.w;
        *(float4*)&Co[o] = v;
      }
    }
  } else {
    __syncthreads();
#pragma unroll
    for (int m = 0; m < 4; m++)
#pragma unroll
      for (int n = 0; n < 4; n++)
#pragma unroll
        for (int r = 0; r < 4; r++)
          lds[(wr * 64 + m * 16 + kg * 4 + r) * 128 + wc * 64 + n * 16 + lm] =
              f2bf(acc[m][n][r]);
    __syncthreads();
    unsigned short* Cu = (unsigned short*)Cout;
#pragma unroll
    for (int j = 0; j < 8; j++) {
      const int idx = t + j * 256;
      const int row = idx >> 4, seg = idx & 15;
      *(uint4*)(Cu + (size_t)(bm + row) * N + bn + seg * 8) =
          *(const uint4*)&lds[row * 128 + seg * 8];
    }
  }
}

// -------- K_A: per-(b,h,chunk) GT = v^T k AND VT write. grid=512, 256 thr ---
__global__ __launch_bounds__(256) void k_chunk_kv(const bf16* __restrict__ qkv,
                                                  float* __restrict__ G,
                                                  bf16* __restrict__ VT) {
  __shared__ __align__(16) unsigned short ks[128][128];
  __shared__ __align__(16) unsigned short vs[128][136];
  const int idx = blockIdx.x;
  const int cc = idx & 31, bh = idx >> 5, bb = bh >> 3, hh = bh & 7;
  const unsigned short* qkvu = (const unsigned short*)qkv;
  const unsigned short* kp = qkvu + (size_t)(bb * 4096 + cc * 128) * 3072 + 1024 + hh * 128;
  const unsigned short* vp = kp + 1024;
  const int t = threadIdx.x;
#pragma unroll
  for (int i = 0; i < 8; i++) {
    int ch = t + i * 256;
    int r = ch >> 4, c8 = (ch & 15) << 3;
    *(uint4*)&ks[r][c8] = *(const uint4*)(kp + (size_t)r * 3072 + c8);
    *(uint4*)&vs[r][c8] = *(const uint4*)(vp + (size_t)r * 3072 + c8);
  }
  __syncthreads();
  const int dv0 = (t >> 4) * 8, dk0 = (t & 15) * 8;
  float acc[8][8] = {};
  for (int j = 0; j < 128; j++) {
    Frag kf, vf;
    vf.u = *(const uint4*)&vs[j][dv0];
    kf.u = *(const uint4*)&ks[j][dk0];
    float kx[8], vx[8];
#pragma unroll
    for (int a = 0; a < 8; a++) { kx[a] = bf2f(kf.s[a]); vx[a] = bf2f(vf.s[a]); }
#pragma unroll
    for (int a = 0; a < 8; a++)
#pragma unroll
      for (int b2 = 0; b2 < 8; b2++) acc[a][b2] += vx[a] * kx[b2];
  }
  float* Gp = G + (size_t)idx * 16384;
#pragma unroll
  for (int a = 0; a < 8; a++)
#pragma unroll
    for (int b2 = 0; b2 < 8; b2 += 4) {
      float4 w4 = make_float4(acc[a][b2], acc[a][b2 + 1], acc[a][b2 + 2], acc[a][b2 + 3]);
      *(float4*)(Gp + (size_t)(dv0 + a) * 128 + dk0 + b2) = w4;
    }
  unsigned short* vo = (unsigned short*)VT + (size_t)bh * 524288 + cc * 128;
#pragma unroll
  for (int i = 0; i < 8; i++) {
    const int dv = (t >> 4) + i * 16;
    const int r0 = (t & 15) * 8;
    Frag f;
#pragma unroll
    for (int j = 0; j < 8; j++) f.s[j] = vs[r0 + j][dv];
    *(uint4*)(vo + (size_t)dv * 4096 + r0) = f.u;
  }
}

// -------- K_B: exclusive prefix over chunks -> ST bf16. grid=1024 -----------
__global__ __launch_bounds__(256) void k_prefix(const float* __restrict__ G,
                                                bf16* __restrict__ S) {
  const size_t gid = (size_t)blockIdx.x * 256 + threadIdx.x;
  const size_t bh = gid >> 14, e = gid & 16383;
  const float* gp = G + (bh << 5) * 16384 + e;
  unsigned short* sp = (unsigned short*)S + (bh << 5) * 16384 + e;
  float run = 0.f;
  for (int c2 = 0; c2 < 32; c2++) {
    sp[(size_t)c2 << 14] = f2bf(run);
    run += gp[(size_t)c2 << 14];
  }
}

// -------- K_C: MFMA fused chunk attention + per-head RMSNorm ----------------
__global__ __launch_bounds__(256) void k_attn2(const bf16* __restrict__ qkv,
                                               const bf16* __restrict__ VT,
                                               const bf16* __restrict__ ST,
                                               const float* __restrict__ nw,
                                               bf16* __restrict__ A2) {
  __shared__ __align__(16) unsigned short Qs[128][136];
  __shared__ __align__(16) unsigned short Ks[128][136];
  __shared__ __align__(16) unsigned short Bs[128][136];
  __shared__ float red[128][2];

  const int idx = blockIdx.x;
  const int cc = idx & 31, bh = idx >> 5, bb = bh >> 3, hh = bh & 7;
  const size_t rowbase = (size_t)(bb * 4096 + cc * 128);
  const unsigned short* qp = (const unsigned short*)qkv + rowbase * 3072 + hh * 128;
  const unsigned short* kp = qp + 1024;
  const unsigned short* vtp = (const unsigned short*)VT + (size_t)bh * 524288 + cc * 128;
  const unsigned short* stp = (const unsigned short*)ST + ((size_t)idx << 14);

  const int t = threadIdx.x;
  const int wid = t >> 6, lane = t & 63;
  const int wm = (wid >> 1) * 64, wn = (wid & 1) * 64;
  const int lm = lane & 15, kg = lane >> 4;
  const int sr = t >> 4;
  const int sc = (t & 15) << 3;

#pragma unroll
  for (int i = 0; i < 8; i++) {
    int r = sr + i * 16;
    *(uint4*)&Qs[r][sc] = *(const uint4*)(qp + (size_t)r * 3072 + sc);
    *(uint4*)&Ks[r][sc] = *(const uint4*)(kp + (size_t)r * 3072 + sc);
    *(uint4*)&Bs[r][sc] = *(const uint4*)(vtp + (size_t)r * 4096 + sc);
  }
  __syncthreads();

  f32x4 acc[4][4] = {};
#pragma unroll
  for (int kk = 0; kk < 4; kk++) {
    Frag af[4], bfr[4];
#pragma unroll
    for (int i = 0; i < 4; i++) {
      af[i].u = *(const uint4*)&Qs[wm + i * 16 + lm][kk * 32 + kg * 8];
      bfr[i].u = *(const uint4*)&Ks[wn + i * 16 + lm][kk * 32 + kg * 8];
    }
#pragma unroll
    for (int mi = 0; mi < 4; mi++)
#pragma unroll
      for (int ni = 0; ni < 4; ni++)
        acc[mi][ni] = __builtin_amdgcn_mfma_f32_16x16x32_bf16(af[mi].b, bfr[ni].b,
                                                              acc[mi][ni], 0, 0, 0);
  }
  __syncthreads();

#pragma unroll
  for (int mi = 0; mi < 4; mi++)
#pragma unroll
    for (int r = 0; r < 4; r++) {
      const int gi = wm + mi * 16 + kg * 4 + r;
#pragma unroll
      for (int ni = 0; ni < 4; ni++) {
        const int gj = wn + ni * 16 + lm;
        Ks[gi][gj] = f2bf(gj <= gi ? acc[mi][ni][r] : 0.f);
      }
    }
  __syncthreads();

  f32x4 oa[4][4] = {};
#pragma unroll
  for (int kk = 0; kk < 4; kk++) {
    Frag af[4], bfr[4];
#pragma unroll
    for (int i = 0; i < 4; i++) {
      af[i].u = *(const uint4*)&Ks[wm + i * 16 + lm][kk * 32 + kg * 8];
      bfr[i].u = *(const uint4*)&Bs[wn + i * 16 + lm][kk * 32 + kg * 8];
    }
#pragma unroll
    for (int mi = 0; mi < 4; mi++)
#pragma unroll
      for (int ni = 0; ni < 4; ni++)
        oa[mi][ni] = __builtin_amdgcn_mfma_f32_16x16x32_bf16(af[mi].b, bfr[ni].b,
                                                             oa[mi][ni], 0, 0, 0);
  }
  __syncthreads();

#pragma unroll
  for (int i = 0; i < 8; i++) {
    int r = sr + i * 16;
    *(uint4*)&Bs[r][sc] = *(const uint4*)(stp + (size_t)r * 128 + sc);
  }
  __syncthreads();

#pragma unroll
  for (int kk = 0; kk < 4; kk++) {
    Frag af[4], bfr[4];
#pragma unroll
    for (int i = 0; i < 4; i++) {
      af[i].u = *(const uint4*)&Qs[wm + i * 16 + lm][kk * 32 + kg * 8];
      bfr[i].u = *(const uint4*)&Bs[wn + i * 16 + lm][kk * 32 + kg * 8];
    }
#pragma unroll
    for (int mi = 0; mi < 4; mi++)
#pragma unroll
      for (int ni = 0; ni < 4; ni++)
        oa[mi][ni] = __builtin_amdgcn_mfma_f32_16x16x32_bf16(af[mi].b, bfr[ni].b,
                                                             oa[mi][ni], 0, 0, 0);
  }

#pragma unroll
  for (int mi = 0; mi < 4; mi++)
#pragma unroll
    for (int r = 0; r < 4; r++) {
      float ss = 0.f;
#pragma unroll
      for (int ni = 0; ni < 4; ni++) ss += oa[mi][ni][r] * oa[mi][ni][r];
      ss += __shfl_xor(ss, 1, 64);
      ss += __shfl_xor(ss, 2, 64);
      ss += __shfl_xor(ss, 4, 64);
      ss += __shfl_xor(ss, 8, 64);
      if (lm == 0) red[wm + mi * 16 + kg * 4 + r][wid & 1] = ss;
    }
  __syncthreads();

#pragma unroll
  for (int mi = 0; mi < 4; mi++)
#pragma unroll
    for (int r = 0; r < 4; r++) {
      const int gi = wm + mi * 16 + kg * 4 + r;
      const float tot = red[gi][0] + red[gi][1];
      const float scl = rsqrtf(tot * (1.f / 128.f) + 1e-5f);
#pragma unroll
      for (int ni = 0; ni < 4; ni++) {
        const int gj = wn + ni * 16 + lm;
        Ks[gi][gj] = f2bf(oa[mi][ni][r] * scl * nw[gj]);
      }
    }
  __syncthreads();

  unsigned short* A2u = (unsigned short*)A2;
#pragma unroll
  for (int i = 0; i < 8; i++) {
    int r = sr + i * 16;
    *(uint4*)(A2u + (rowbase + r) * 1024 + hh * 128 + sc) = *(const uint4*)&Ks[r][sc];
  }
}

// ---------------------------------------------------------------------------
extern "C" void kernel_launch(void* const* d_in, const int* in_sizes, int n_in,
                              void* d_out, int out_size, void* d_ws, size_t ws_size,
                              hipStream_t stream) {
  const float* x = (const float*)d_in[0];
  const float* anw = (const float*)d_in[1];
  const float* Wq = (const float*)d_in[2];
  const float* Wk = (const float*)d_in[3];
  const float* Wv = (const float*)d_in[4];
  const float* Wo = (const float*)d_in[5];
  const float* onw = (const float*)d_in[6];
  const float* mnw = (const float*)d_in[7];
  const float* Wg = (const float*)d_in[8];
  const float* Wu = (const float*)d_in[9];
  const float* Wd = (const float*)d_in[10];
  float* out = (float*)d_out;

  char* base = (char*)d_ws;
  size_t off = 0;
  auto alloc = [&](size_t bytes) -> char* {
    char* q = base + off;
    off += (bytes + 255) & ~(size_t)255;
    return q;
  };
  bf16* WqkvT = (bf16*)alloc(3072ll * 1024 * 2);
  bf16* WoT   = (bf16*)alloc(1024ll * 1024 * 2);
  bf16* WguT  = (bf16*)alloc(8192ll * 1024 * 2);   // interleaved gate|up (128-col)
  bf16* WdT   = (bf16*)alloc(1024ll * 4096 * 2);
  bf16* h     = (bf16*)alloc(8192ll * 1024 * 2);
  float* x1   = (float*)alloc(8192ll * 1024 * 4);
  char* pool  = alloc(8192ll * 3072 * 2 + 16ll * 32 * 16384 * 4 +
                      16ll * 32 * 16384 * 2 + 16ll * 128 * 4096 * 2);
  bf16* qkv = (bf16*)pool;
  float* G  = (float*)(pool + 8192ll * 3072 * 2);
  bf16* S   = (bf16*)(pool + 8192ll * 3072 * 2 + 16ll * 32 * 16384 * 4);
  bf16* VT  = (bf16*)(pool + 8192ll * 3072 * 2 + 16ll * 32 * 16384 * 4 +
                      16ll * 32 * 16384 * 2);
  bf16* act = (bf16*)pool;  // MLP phase reuse

  const dim3 tb32(32, 8);
  TP4 tp;
  tp.s[0] = Wq; tp.d[0] = WqkvT;
  tp.s[1] = Wk; tp.d[1] = WqkvT + 1024ll * 1024;
  tp.s[2] = Wv; tp.d[2] = WqkvT + 2048ll * 1024;
  tp.s[3] = Wo; tp.d[3] = WoT;
  k_transpose_w4<<<dim3(32, 32, 4), tb32, 0, stream>>>(tp);
  k_transpose_wgu<<<dim3(128, 32, 2), tb32, 0, stream>>>(Wg, Wu, WguT);
  k_transpose_w<<<dim3(32, 128), tb32, 0, stream>>>(Wd, WdT, 4096, 1024);

  // attn sub-block
  k_rmsnorm<<<8192, 256, 0, stream>>>(x, anw, h);
  k_gemm128<0><<<dim3(24, 64), 256, 0, stream>>>(h, 1024, WqkvT, nullptr, qkv, 3072, 1024);
  k_chunk_kv<<<512, 256, 0, stream>>>(qkv, G, VT);
  k_prefix<<<1024, 256, 0, stream>>>(G, S);
  k_attn2<<<512, 256, 0, stream>>>(qkv, VT, S, onw, h);
  k_gemm128<1><<<dim3(8, 64), 256, 0, stream>>>(h, 1024, WoT, x, x1, 1024, 1024);

  // mlp sub-block
  k_rmsnorm<<<8192, 256, 0, stream>>>(x1, mnw, h);
  k_gemm256<256, 3><<<dim3(32, 32), 512, 0, stream>>>(h, 1024, WguT, nullptr, act, 8192, 1024);
  k_gemm128<1><<<dim3(8, 64), 256, 0, stream>>>(act, 4096, WdT, x1, out, 1024, 4096);
}